// Round 1
// baseline (839.647 us; speedup 1.0000x reference)
//
#include <hip/hip_runtime.h>
#include <math.h>

#define BATCH 256
#define NPTS  16384
#define TPB   256

// pass1 tiling
#define P1_CHUNKS     4
#define P1_PTS_BLOCK  (NPTS / P1_CHUNKS)      // 4096
#define P1_PTS_THREAD (P1_PTS_BLOCK / TPB)    // 16

// pass2 tiling
#define P2_CHUNKS     8
#define P2_PTS_BLOCK  (NPTS / P2_CHUNKS)      // 2048
#define P2_PTS_THREAD (P2_PTS_BLOCK / TPB)    // 8

// ---- workspace layout (32-bit word offsets) ----
// R1: per batch stride 256 words:
//   [0..2]   sumX (coords)
//   [3..8]   sumXX (xx,xy,xz,yy,yz,zz)
//   [9..72]  chMax[64]   (float bits, values >= 0, uint atomicMax)
//   [73..136] chSum[64]
//   [137..200] chSumSq[64]
#define R1_STRIDE 256
#define R1_WORDS  (BATCH * R1_STRIDE)         // 65536
// R2: per batch stride 32 words: [0..8] evecs (e*3+comp), [9..11] eig_norm, [12..14] centroid
#define R2_OFF    R1_WORDS
#define R2_STRIDE 32
#define R2_WORDS  (BATCH * R2_STRIDE)         // 8192
// R3: monotone-mapped uint keys for proj max/min, 4 words per batch each
#define R3MAX_OFF (R2_OFF + R2_WORDS)         // 73728
#define R3MIN_OFF (R3MAX_OFF + BATCH * 4)     // 74752
#define WS_WORDS  (R3MIN_OFF + BATCH * 4)     // 75776 words = ~296 KB

__device__ __forceinline__ unsigned floatToKey(float f) {
    unsigned u = __float_as_uint(f);
    return (u & 0x80000000u) ? ~u : (u | 0x80000000u);
}
__device__ __forceinline__ float keyToFloat(unsigned k) {
    unsigned u = (k & 0x80000000u) ? (k ^ 0x80000000u) : ~k;
    return __uint_as_float(u);
}

// ---------------- init: zero accumulators, set min/max sentinels ----------------
__global__ void init_ws_kernel(unsigned* __restrict__ wsu) {
    int i = blockIdx.x * TPB + threadIdx.x;
    if (i < R1_WORDS) wsu[i] = 0u;
    if (i < BATCH * 4) {
        wsu[R3MAX_OFF + i] = 0u;           // smaller than any finite float key
        wsu[R3MIN_OFF + i] = 0xFFFFFFFFu;  // larger than any finite float key
    }
}

// ---------------- pass 1: coord moments + point MLP + channel stats ----------------
// grid: (BATCH, P1_CHUNKS, 2)  -- z selects channel half [z*32, z*32+32)
__global__ __launch_bounds__(TPB, 2)
void pass1_kernel(const float* __restrict__ x, const float* __restrict__ W1,
                  const float* __restrict__ b1, const float* __restrict__ W2,
                  const float* __restrict__ b2, float* __restrict__ ws) {
    const int b     = blockIdx.x;
    const int chunk = blockIdx.y;
    const int half  = blockIdx.z;
    const int tid   = threadIdx.x;
    const int lane  = tid & 63;
    const int wave  = tid >> 6;

    const float* xb = x + ((size_t)b * NPTS + (size_t)chunk * P1_PTS_BLOCK) * 5;

    float sx = 0.f, sy = 0.f, sz = 0.f;
    float sxx = 0.f, sxy = 0.f, sxz = 0.f, syy = 0.f, syz = 0.f, szz = 0.f;
    float vmax[32], vsum[32], vsq[32];
#pragma unroll
    for (int c = 0; c < 32; ++c) { vmax[c] = 0.f; vsum[c] = 0.f; vsq[c] = 0.f; }

    for (int i = 0; i < P1_PTS_THREAD; ++i) {
        const float* p = xb + (size_t)(i * TPB + tid) * 5;
        float c0 = p[0], c1 = p[1], c2 = p[2], s0 = p[3], s1 = p[4];
        if (half == 0) {
            sx += c0; sy += c1; sz += c2;
            sxx = fmaf(c0, c0, sxx); sxy = fmaf(c0, c1, sxy); sxz = fmaf(c0, c2, sxz);
            syy = fmaf(c1, c1, syy); syz = fmaf(c1, c2, syz); szz = fmaf(c2, c2, szz);
        }
        // layer 1: sem(2) -> 32, relu
        float pf1[32];
#pragma unroll
        for (int j = 0; j < 32; ++j)
            pf1[j] = fmaxf(0.f, fmaf(s0, W1[j], fmaf(s1, W1[32 + j], b1[j])));
        // layer 2 (this block's 32-channel half), relu, stats
        float acc[32];
#pragma unroll
        for (int c = 0; c < 32; ++c) acc[c] = b2[half * 32 + c];
#pragma unroll
        for (int k = 0; k < 32; ++k) {
            float a = pf1[k];
            const float* wrow = W2 + k * 64 + half * 32;
#pragma unroll
            for (int c = 0; c < 32; ++c) acc[c] = fmaf(a, wrow[c], acc[c]);
        }
#pragma unroll
        for (int c = 0; c < 32; ++c) {
            float r = fmaxf(acc[c], 0.f);
            vmax[c] = fmaxf(vmax[c], r);
            vsum[c] += r;
            vsq[c] = fmaf(r, r, vsq[c]);
        }
    }

    // wave-level shuffle reductions, then cross-wave combine in LDS
    __shared__ float red[4][112];
#pragma unroll
    for (int c = 0; c < 32; ++c) {
        float v = vmax[c];
#pragma unroll
        for (int o = 32; o > 0; o >>= 1) v = fmaxf(v, __shfl_xor(v, o));
        if (lane == 0) red[wave][c] = v;
    }
#pragma unroll
    for (int c = 0; c < 32; ++c) {
        float v = vsum[c];
#pragma unroll
        for (int o = 32; o > 0; o >>= 1) v += __shfl_xor(v, o);
        if (lane == 0) red[wave][32 + c] = v;
    }
#pragma unroll
    for (int c = 0; c < 32; ++c) {
        float v = vsq[c];
#pragma unroll
        for (int o = 32; o > 0; o >>= 1) v += __shfl_xor(v, o);
        if (lane == 0) red[wave][64 + c] = v;
    }
    if (half == 0) {
        float cv[9] = {sx, sy, sz, sxx, sxy, sxz, syy, syz, szz};
#pragma unroll
        for (int j = 0; j < 9; ++j) {
            float v = cv[j];
#pragma unroll
            for (int o = 32; o > 0; o >>= 1) v += __shfl_xor(v, o);
            if (lane == 0) red[wave][96 + j] = v;
        }
    }
    __syncthreads();

    const int nvals = (half == 0) ? 105 : 96;
    if (tid < nvals) {
        float v0 = red[0][tid], v1 = red[1][tid], v2 = red[2][tid], v3 = red[3][tid];
        float* base = ws + (size_t)b * R1_STRIDE;
        if (tid < 32) {
            float m = fmaxf(fmaxf(v0, v1), fmaxf(v2, v3));   // values >= 0
            atomicMax((unsigned*)(base + 9 + half * 32 + tid), __float_as_uint(m));
        } else if (tid < 64) {
            atomicAdd(base + 73 + half * 32 + (tid - 32), v0 + v1 + v2 + v3);
        } else if (tid < 96) {
            atomicAdd(base + 137 + half * 32 + (tid - 64), v0 + v1 + v2 + v3);
        } else {
            atomicAdd(base + (tid - 96), v0 + v1 + v2 + v3);  // sumX[3] then sumXX[6]
        }
    }
}

// ---------------- eigh: 3x3 Jacobi (fp64) per batch ----------------
__global__ void eigh_kernel(float* __restrict__ ws) {
    int b = blockIdx.x * blockDim.x + threadIdx.x;
    if (b >= BATCH) return;
    const float* r1 = ws + (size_t)b * R1_STRIDE;
    const double n = (double)NPTS;
    double mx = r1[0] / n, my = r1[1] / n, mz = r1[2] / n;
    double A[3][3];
    A[0][0] = r1[3] / n - mx * mx; A[0][1] = r1[4] / n - mx * my; A[0][2] = r1[5] / n - mx * mz;
    A[1][1] = r1[6] / n - my * my; A[1][2] = r1[7] / n - my * mz; A[2][2] = r1[8] / n - mz * mz;
    A[1][0] = A[0][1]; A[2][0] = A[0][2]; A[2][1] = A[1][2];
    double V[3][3] = {{1, 0, 0}, {0, 1, 0}, {0, 0, 1}};

    const int PP[3] = {0, 0, 1};
    const int QQ[3] = {1, 2, 2};
    for (int sweep = 0; sweep < 12; ++sweep) {
        for (int r3 = 0; r3 < 3; ++r3) {
            int p = PP[r3], q = QQ[r3];
            double apq = A[p][q];
            if (fabs(apq) < 1e-300) continue;
            double theta = (A[q][q] - A[p][p]) / (2.0 * apq);
            double t = 1.0 / (fabs(theta) + sqrt(theta * theta + 1.0));
            if (theta < 0.0) t = -t;
            double c = 1.0 / sqrt(t * t + 1.0), s = t * c;
            double app = A[p][p], aqq = A[q][q];
            A[p][p] = app - t * apq;
            A[q][q] = aqq + t * apq;
            A[p][q] = A[q][p] = 0.0;
            for (int r = 0; r < 3; ++r) {
                if (r != p && r != q) {
                    double arp = A[r][p], arq = A[r][q];
                    A[r][p] = A[p][r] = c * arp - s * arq;
                    A[r][q] = A[q][r] = s * arp + c * arq;
                }
                double vrp = V[r][p], vrq = V[r][q];
                V[r][p] = c * vrp - s * vrq;
                V[r][q] = s * vrp + c * vrq;
            }
        }
    }
    double w[3] = {A[0][0], A[1][1], A[2][2]};
    int i0 = 0, i1 = 1, i2 = 2, t;
    if (w[i0] < w[i1]) { t = i0; i0 = i1; i1 = t; }
    if (w[i0] < w[i2]) { t = i0; i0 = i2; i2 = t; }
    if (w[i1] < w[i2]) { t = i1; i1 = i2; i2 = t; }
    int idx[3] = {i0, i1, i2};

    float* r2 = ws + R2_OFF + (size_t)b * R2_STRIDE;
    for (int e = 0; e < 3; ++e)
        for (int comp = 0; comp < 3; ++comp)
            r2[e * 3 + comp] = (float)V[comp][idx[e]];
    double sum = w[0] + w[1] + w[2] + 1e-8;
    for (int e = 0; e < 3; ++e) r2[9 + e] = (float)(w[idx[e]] / sum);
    r2[12] = (float)mx; r2[13] = (float)my; r2[14] = (float)mz;
}

// ---------------- pass 2: projections min/max (extents) ----------------
// grid: (BATCH, P2_CHUNKS)
__global__ __launch_bounds__(TPB)
void pass2_kernel(const float* __restrict__ x, float* __restrict__ ws) {
    const int b = blockIdx.x, chunk = blockIdx.y, tid = threadIdx.x;
    const int lane = tid & 63, wave = tid >> 6;
    const float* r2 = ws + R2_OFF + (size_t)b * R2_STRIDE;
    float e0x = r2[0], e0y = r2[1], e0z = r2[2];
    float e1x = r2[3], e1y = r2[4], e1z = r2[5];
    float e2x = r2[6], e2y = r2[7], e2z = r2[8];
    float cx = r2[12], cy = r2[13], cz = r2[14];

    const float* xb = x + ((size_t)b * NPTS + (size_t)chunk * P2_PTS_BLOCK) * 5;
    float mn[3] = {3.4e38f, 3.4e38f, 3.4e38f};
    float mx[3] = {-3.4e38f, -3.4e38f, -3.4e38f};
    for (int i = 0; i < P2_PTS_THREAD; ++i) {
        const float* p = xb + (size_t)(i * TPB + tid) * 5;
        float c0 = p[0] - cx, c1 = p[1] - cy, c2 = p[2] - cz;
        float p0 = fmaf(c0, e0x, fmaf(c1, e0y, c2 * e0z));
        float p1 = fmaf(c0, e1x, fmaf(c1, e1y, c2 * e1z));
        float p2 = fmaf(c0, e2x, fmaf(c1, e2y, c2 * e2z));
        mn[0] = fminf(mn[0], p0); mx[0] = fmaxf(mx[0], p0);
        mn[1] = fminf(mn[1], p1); mx[1] = fmaxf(mx[1], p1);
        mn[2] = fminf(mn[2], p2); mx[2] = fmaxf(mx[2], p2);
    }
    __shared__ float red[4][8];
#pragma unroll
    for (int d = 0; d < 3; ++d) {
        float v = mx[d];
#pragma unroll
        for (int o = 32; o > 0; o >>= 1) v = fmaxf(v, __shfl_xor(v, o));
        if (lane == 0) red[wave][d] = v;
    }
#pragma unroll
    for (int d = 0; d < 3; ++d) {
        float v = mn[d];
#pragma unroll
        for (int o = 32; o > 0; o >>= 1) v = fminf(v, __shfl_xor(v, o));
        if (lane == 0) red[wave][4 + d] = v;
    }
    __syncthreads();
    unsigned* wsu = (unsigned*)ws;
    if (tid < 3) {
        float m = fmaxf(fmaxf(red[0][tid], red[1][tid]), fmaxf(red[2][tid], red[3][tid]));
        atomicMax(&wsu[R3MAX_OFF + b * 4 + tid], floatToKey(m));
    } else if (tid < 6) {
        int d = tid - 3;
        float m = fminf(fminf(red[0][4 + d], red[1][4 + d]), fminf(red[2][4 + d], red[3][4 + d]));
        atomicMin(&wsu[R3MIN_OFF + b * 4 + d], floatToKey(m));
    }
}

// ---------------- final: assemble g(201) and run 201->256->128->256 MLP ----------------
__global__ __launch_bounds__(TPB)
void final_kernel(const float* __restrict__ W3, const float* __restrict__ b3,
                  const float* __restrict__ W4, const float* __restrict__ b4,
                  const float* __restrict__ W5, const float* __restrict__ b5,
                  const float* __restrict__ ws, float* __restrict__ out) {
    const int b = blockIdx.x, t = threadIdx.x;
    __shared__ float g[224];
    __shared__ float h1[256];
    __shared__ float h2[128];
    const float* r1 = ws + (size_t)b * R1_STRIDE;
    if (t < 64) {
        g[t] = r1[9 + t];                       // gmax (bits written by uint atomicMax)
        float s = r1[73 + t], sq = r1[137 + t];
        float avg = s * (1.0f / NPTS);
        g[64 + t] = avg;
        float var = (sq - s * avg) / (float)(NPTS - 1);   // ddof=1
        g[128 + t] = sqrtf(fmaxf(var, 0.f));
    } else if (t < 73) {
        int j = t - 64;
        const float* r2 = ws + R2_OFF + (size_t)b * R2_STRIDE;
        const unsigned* wsu = (const unsigned*)ws;
        if (j < 3) {
            g[192 + j] = r2[9 + j];             // eig_norm
        } else if (j < 6) {
            int d = j - 3;
            float fmx = keyToFloat(wsu[R3MAX_OFF + b * 4 + d]);
            float fmn = keyToFloat(wsu[R3MIN_OFF + b * 4 + d]);
            g[195 + d] = fmx - fmn;             // extents
        } else {
            g[198 + (j - 6)] = r2[12 + (j - 6)]; // centroid
        }
    }
    __syncthreads();
    float a = b3[t];
    for (int j = 0; j < 201; ++j) a = fmaf(g[j], W3[j * 256 + t], a);
    h1[t] = fmaxf(a, 0.f);
    __syncthreads();
    if (t < 128) {
        float a2 = b4[t];
        for (int j = 0; j < 256; ++j) a2 = fmaf(h1[j], W4[j * 128 + t], a2);
        h2[t] = fmaxf(a2, 0.f);
    }
    __syncthreads();
    float o = b5[t];
    for (int j = 0; j < 128; ++j) o = fmaf(h2[j], W5[j * 256 + t], o);
    out[(size_t)b * 256 + t] = o;
}

extern "C" void kernel_launch(void* const* d_in, const int* in_sizes, int n_in,
                              void* d_out, int out_size, void* d_ws, size_t ws_size,
                              hipStream_t stream) {
    const float* x  = (const float*)d_in[0];
    const float* W1 = (const float*)d_in[1];
    const float* b1 = (const float*)d_in[2];
    const float* W2 = (const float*)d_in[3];
    const float* b2 = (const float*)d_in[4];
    const float* W3 = (const float*)d_in[5];
    const float* b3 = (const float*)d_in[6];
    const float* W4 = (const float*)d_in[7];
    const float* b4 = (const float*)d_in[8];
    const float* W5 = (const float*)d_in[9];
    const float* b5 = (const float*)d_in[10];
    float* out = (float*)d_out;
    float* ws  = (float*)d_ws;

    init_ws_kernel<<<dim3(R1_WORDS / TPB), TPB, 0, stream>>>((unsigned*)ws);
    pass1_kernel<<<dim3(BATCH, P1_CHUNKS, 2), TPB, 0, stream>>>(x, W1, b1, W2, b2, ws);
    eigh_kernel<<<dim3(4), 64, 0, stream>>>(ws);
    pass2_kernel<<<dim3(BATCH, P2_CHUNKS), TPB, 0, stream>>>(x, ws);
    final_kernel<<<dim3(BATCH), TPB, 0, stream>>>(W3, b3, W4, b4, W5, b5, ws, out);
}

// Round 2
// 230.872 us; speedup vs baseline: 3.6369x; 3.6369x over previous
//
#include <hip/hip_runtime.h>
#include <math.h>

#define BATCH 256
#define NPTS  16384
#define TPB   256

// pass1 tiling: grid (BATCH, P1_CHUNKS); 4 waves/block; wave handles 512 pts
#define P1_CHUNKS     8
#define P1_PTS_BLOCK  (NPTS / P1_CHUNKS)      // 2048
#define P1_ITERS      8                        // 8 iters x 64 pts = 512 pts/wave

// pass2 tiling
#define P2_CHUNKS     8
#define P2_PTS_BLOCK  (NPTS / P2_CHUNKS)      // 2048
#define P2_PTS_THREAD (P2_PTS_BLOCK / TPB)    // 8

// ---- workspace layout (32-bit word offsets) ----
// R1 per batch (stride 256): [0..2] sumX, [3..8] sumXX, [9..72] chMax[64],
//                            [73..136] chSum[64], [137..200] chSumSq[64]
#define R1_STRIDE 256
#define R1_WORDS  (BATCH * R1_STRIDE)
#define R2_OFF    R1_WORDS
#define R2_STRIDE 32
#define R2_WORDS  (BATCH * R2_STRIDE)
#define R3MAX_OFF (R2_OFF + R2_WORDS)
#define R3MIN_OFF (R3MAX_OFF + BATCH * 4)

typedef __bf16 bf16x8 __attribute__((ext_vector_type(8)));
typedef float  floatx4 __attribute__((ext_vector_type(4)));

__device__ __forceinline__ unsigned floatToKey(float f) {
    unsigned u = __float_as_uint(f);
    return (u & 0x80000000u) ? ~u : (u | 0x80000000u);
}
__device__ __forceinline__ float keyToFloat(unsigned k) {
    unsigned u = (k & 0x80000000u) ? (k ^ 0x80000000u) : ~k;
    return __uint_as_float(u);
}

// ---------------- init ----------------
__global__ void init_ws_kernel(unsigned* __restrict__ wsu) {
    int i = blockIdx.x * TPB + threadIdx.x;
    if (i < R1_WORDS) wsu[i] = 0u;
    if (i < BATCH * 4) {
        wsu[R3MAX_OFF + i] = 0u;
        wsu[R3MIN_OFF + i] = 0xFFFFFFFFu;
    }
}

// ---------------- pass 1: coord moments + MFMA point-MLP + channel stats ----------------
// A-frag layout (16x16x32 bf16): A[m = lane&15][k = (lane>>4)*8 + j]
// B-frag layout:                 B[k = (lane>>4)*8 + j][n = lane&15]
// C/D layout:                    col = lane&15, row = (lane>>4)*4 + reg   [m89]
__global__ __launch_bounds__(TPB, 4)
void pass1_kernel(const float* __restrict__ x, const float* __restrict__ W1,
                  const float* __restrict__ b1, const float* __restrict__ W2,
                  const float* __restrict__ b2, float* __restrict__ ws) {
    const int b     = blockIdx.x;
    const int chunk = blockIdx.y;
    const int tid   = threadIdx.x;
    const int lane  = tid & 63;
    const int wave  = tid >> 6;
    const int quad  = lane >> 4;
    const int l15   = lane & 15;

    // --- per-lane constant fragments ---
    // W2 (32x64) as 4 B-frags (16-channel tiles); bias per (tile, l15)
    bf16x8 Bf[4];
    float  b2n[4];
#pragma unroll
    for (int t = 0; t < 4; ++t) {
        int n = t * 16 + l15;
#pragma unroll
        for (int j = 0; j < 8; ++j)
            Bf[t][j] = (__bf16)W2[(quad * 8 + j) * 64 + n];
        b2n[t] = b2[n];
    }
    // layer-1 weights for this lane's k-range (k = quad*8 + j)
    float w1a[8], w1b[8], b1r[8];
#pragma unroll
    for (int j = 0; j < 8; ++j) {
        int jj = quad * 8 + j;
        w1a[j] = W1[jj];
        w1b[j] = W1[32 + jj];
        b1r[j] = b1[jj];
    }

    float vmax[4] = {0.f, 0.f, 0.f, 0.f};
    float vsum[4] = {0.f, 0.f, 0.f, 0.f};
    float vsq[4]  = {0.f, 0.f, 0.f, 0.f};
    float mo[9];
#pragma unroll
    for (int j = 0; j < 9; ++j) mo[j] = 0.f;

    const float* xb = x + ((size_t)b * NPTS + (size_t)chunk * P1_PTS_BLOCK) * 5;

    for (int it = 0; it < P1_ITERS; ++it) {
        const int pbase = wave * (P1_ITERS * 64) + it * 64;
        const float* p = xb + (size_t)(pbase + lane) * 5;
        float c0 = p[0], c1 = p[1], c2 = p[2], s0 = p[3], s1 = p[4];
        // coordinate moments (this lane's own point)
        mo[0] += c0; mo[1] += c1; mo[2] += c2;
        mo[3] = fmaf(c0, c0, mo[3]); mo[4] = fmaf(c0, c1, mo[4]); mo[5] = fmaf(c0, c2, mo[5]);
        mo[6] = fmaf(c1, c1, mo[6]); mo[7] = fmaf(c1, c2, mo[7]); mo[8] = fmaf(c1 == c1 ? c2 : c2, c2, mo[8]);

        // 4 groups of 16 points; lane computes pf1[point g*16+l15][k=quad*8+j]
#pragma unroll
        for (int g = 0; g < 4; ++g) {
            int src = g * 16 + l15;
            float gs0 = __shfl(s0, src);
            float gs1 = __shfl(s1, src);
            bf16x8 Af;
#pragma unroll
            for (int j = 0; j < 8; ++j) {
                float v = fmaf(gs0, w1a[j], fmaf(gs1, w1b[j], b1r[j]));
                Af[j] = (__bf16)fmaxf(v, 0.f);
            }
#pragma unroll
            for (int t = 0; t < 4; ++t) {
                floatx4 C = {0.f, 0.f, 0.f, 0.f};
                C = __builtin_amdgcn_mfma_f32_16x16x32_bf16(Af, Bf[t], C, 0, 0, 0);
#pragma unroll
                for (int r = 0; r < 4; ++r) {
                    float v = fmaxf(C[r] + b2n[t], 0.f);
                    vmax[t] = fmaxf(vmax[t], v);
                    vsum[t] += v;
                    vsq[t]  = fmaf(v, v, vsq[t]);
                }
            }
        }
    }

    // --- wave-level reduction: combine quads (lanes sharing l15) ---
#pragma unroll
    for (int t = 0; t < 4; ++t) {
        vmax[t] = fmaxf(vmax[t], __shfl_xor(vmax[t], 16));
        vmax[t] = fmaxf(vmax[t], __shfl_xor(vmax[t], 32));
        vsum[t] += __shfl_xor(vsum[t], 16);
        vsum[t] += __shfl_xor(vsum[t], 32);
        vsq[t]  += __shfl_xor(vsq[t], 16);
        vsq[t]  += __shfl_xor(vsq[t], 32);
    }
#pragma unroll
    for (int j = 0; j < 9; ++j) {
        float v = mo[j];
#pragma unroll
        for (int o = 32; o > 0; o >>= 1) v += __shfl_xor(v, o);
        mo[j] = v;
    }

    __shared__ float red[4][201];
    if (quad == 0) {
#pragma unroll
        for (int t = 0; t < 4; ++t) {
            red[wave][t * 16 + l15]       = vmax[t];
            red[wave][64 + t * 16 + l15]  = vsum[t];
            red[wave][128 + t * 16 + l15] = vsq[t];
        }
    }
    if (lane == 0) {
#pragma unroll
        for (int j = 0; j < 9; ++j) red[wave][192 + j] = mo[j];
    }
    __syncthreads();

    if (tid < 201) {
        float v0 = red[0][tid], v1 = red[1][tid], v2 = red[2][tid], v3 = red[3][tid];
        float* base = ws + (size_t)b * R1_STRIDE;
        if (tid < 64) {
            float m = fmaxf(fmaxf(v0, v1), fmaxf(v2, v3));   // relu'd values >= 0
            atomicMax((unsigned*)(base + 9 + tid), __float_as_uint(m));
        } else if (tid < 128) {
            atomicAdd(base + 73 + (tid - 64), v0 + v1 + v2 + v3);
        } else if (tid < 192) {
            atomicAdd(base + 137 + (tid - 128), v0 + v1 + v2 + v3);
        } else {
            atomicAdd(base + (tid - 192), v0 + v1 + v2 + v3);
        }
    }
}

// ---------------- eigh: 3x3 Jacobi (fp64) per batch ----------------
__global__ void eigh_kernel(float* __restrict__ ws) {
    int b = blockIdx.x * blockDim.x + threadIdx.x;
    if (b >= BATCH) return;
    const float* r1 = ws + (size_t)b * R1_STRIDE;
    const double n = (double)NPTS;
    double mx = r1[0] / n, my = r1[1] / n, mz = r1[2] / n;
    double A[3][3];
    A[0][0] = r1[3] / n - mx * mx; A[0][1] = r1[4] / n - mx * my; A[0][2] = r1[5] / n - mx * mz;
    A[1][1] = r1[6] / n - my * my; A[1][2] = r1[7] / n - my * mz; A[2][2] = r1[8] / n - mz * mz;
    A[1][0] = A[0][1]; A[2][0] = A[0][2]; A[2][1] = A[1][2];
    double V[3][3] = {{1, 0, 0}, {0, 1, 0}, {0, 0, 1}};

    const int PP[3] = {0, 0, 1};
    const int QQ[3] = {1, 2, 2};
    for (int sweep = 0; sweep < 12; ++sweep) {
        for (int r3 = 0; r3 < 3; ++r3) {
            int p = PP[r3], q = QQ[r3];
            double apq = A[p][q];
            if (fabs(apq) < 1e-300) continue;
            double theta = (A[q][q] - A[p][p]) / (2.0 * apq);
            double t = 1.0 / (fabs(theta) + sqrt(theta * theta + 1.0));
            if (theta < 0.0) t = -t;
            double c = 1.0 / sqrt(t * t + 1.0), s = t * c;
            double apq_t = t * apq;
            A[p][p] -= apq_t;
            A[q][q] += apq_t;
            A[p][q] = A[q][p] = 0.0;
            for (int r = 0; r < 3; ++r) {
                if (r != p && r != q) {
                    double arp = A[r][p], arq = A[r][q];
                    A[r][p] = A[p][r] = c * arp - s * arq;
                    A[r][q] = A[q][r] = s * arp + c * arq;
                }
                double vrp = V[r][p], vrq = V[r][q];
                V[r][p] = c * vrp - s * vrq;
                V[r][q] = s * vrp + c * vrq;
            }
        }
    }
    double w[3] = {A[0][0], A[1][1], A[2][2]};
    int i0 = 0, i1 = 1, i2 = 2, t;
    if (w[i0] < w[i1]) { t = i0; i0 = i1; i1 = t; }
    if (w[i0] < w[i2]) { t = i0; i0 = i2; i2 = t; }
    if (w[i1] < w[i2]) { t = i1; i1 = i2; i2 = t; }
    int idx[3] = {i0, i1, i2};

    float* r2 = ws + R2_OFF + (size_t)b * R2_STRIDE;
    for (int e = 0; e < 3; ++e)
        for (int comp = 0; comp < 3; ++comp)
            r2[e * 3 + comp] = (float)V[comp][idx[e]];
    double sum = w[0] + w[1] + w[2] + 1e-8;
    for (int e = 0; e < 3; ++e) r2[9 + e] = (float)(w[idx[e]] / sum);
    r2[12] = (float)mx; r2[13] = (float)my; r2[14] = (float)mz;
}

// ---------------- pass 2: projection extents ----------------
__global__ __launch_bounds__(TPB)
void pass2_kernel(const float* __restrict__ x, float* __restrict__ ws) {
    const int b = blockIdx.x, chunk = blockIdx.y, tid = threadIdx.x;
    const int lane = tid & 63, wave = tid >> 6;
    const float* r2 = ws + R2_OFF + (size_t)b * R2_STRIDE;
    float e0x = r2[0], e0y = r2[1], e0z = r2[2];
    float e1x = r2[3], e1y = r2[4], e1z = r2[5];
    float e2x = r2[6], e2y = r2[7], e2z = r2[8];
    float cx = r2[12], cy = r2[13], cz = r2[14];

    const float* xb = x + ((size_t)b * NPTS + (size_t)chunk * P2_PTS_BLOCK) * 5;
    float mn[3] = {3.4e38f, 3.4e38f, 3.4e38f};
    float mx[3] = {-3.4e38f, -3.4e38f, -3.4e38f};
    for (int i = 0; i < P2_PTS_THREAD; ++i) {
        const float* p = xb + (size_t)(i * TPB + tid) * 5;
        float c0 = p[0] - cx, c1 = p[1] - cy, c2 = p[2] - cz;
        float p0 = fmaf(c0, e0x, fmaf(c1, e0y, c2 * e0z));
        float p1 = fmaf(c0, e1x, fmaf(c1, e1y, c2 * e1z));
        float p2 = fmaf(c0, e2x, fmaf(c1, e2y, c2 * e2z));
        mn[0] = fminf(mn[0], p0); mx[0] = fmaxf(mx[0], p0);
        mn[1] = fminf(mn[1], p1); mx[1] = fmaxf(mx[1], p1);
        mn[2] = fminf(mn[2], p2); mx[2] = fmaxf(mx[2], p2);
    }
    __shared__ float red[4][8];
#pragma unroll
    for (int d = 0; d < 3; ++d) {
        float v = mx[d];
#pragma unroll
        for (int o = 32; o > 0; o >>= 1) v = fmaxf(v, __shfl_xor(v, o));
        if (lane == 0) red[wave][d] = v;
    }
#pragma unroll
    for (int d = 0; d < 3; ++d) {
        float v = mn[d];
#pragma unroll
        for (int o = 32; o > 0; o >>= 1) v = fminf(v, __shfl_xor(v, o));
        if (lane == 0) red[wave][4 + d] = v;
    }
    __syncthreads();
    unsigned* wsu = (unsigned*)ws;
    if (tid < 3) {
        float m = fmaxf(fmaxf(red[0][tid], red[1][tid]), fmaxf(red[2][tid], red[3][tid]));
        atomicMax(&wsu[R3MAX_OFF + b * 4 + tid], floatToKey(m));
    } else if (tid < 6) {
        int d = tid - 3;
        float m = fminf(fminf(red[0][4 + d], red[1][4 + d]), fminf(red[2][4 + d], red[3][4 + d]));
        atomicMin(&wsu[R3MIN_OFF + b * 4 + d], floatToKey(m));
    }
}

// ---------------- final MLP 201->256->128->256 ----------------
__global__ __launch_bounds__(TPB)
void final_kernel(const float* __restrict__ W3, const float* __restrict__ b3,
                  const float* __restrict__ W4, const float* __restrict__ b4,
                  const float* __restrict__ W5, const float* __restrict__ b5,
                  const float* __restrict__ ws, float* __restrict__ out) {
    const int b = blockIdx.x, t = threadIdx.x;
    __shared__ float g[224];
    __shared__ float h1[256];
    __shared__ float h2[128];
    const float* r1 = ws + (size_t)b * R1_STRIDE;
    if (t < 64) {
        g[t] = r1[9 + t];
        float s = r1[73 + t], sq = r1[137 + t];
        float avg = s * (1.0f / NPTS);
        g[64 + t] = avg;
        float var = (sq - s * avg) / (float)(NPTS - 1);
        g[128 + t] = sqrtf(fmaxf(var, 0.f));
    } else if (t < 73) {
        int j = t - 64;
        const float* r2 = ws + R2_OFF + (size_t)b * R2_STRIDE;
        const unsigned* wsu = (const unsigned*)ws;
        if (j < 3) {
            g[192 + j] = r2[9 + j];
        } else if (j < 6) {
            int d = j - 3;
            float fmx = keyToFloat(wsu[R3MAX_OFF + b * 4 + d]);
            float fmn = keyToFloat(wsu[R3MIN_OFF + b * 4 + d]);
            g[195 + d] = fmx - fmn;
        } else {
            g[198 + (j - 6)] = r2[12 + (j - 6)];
        }
    }
    __syncthreads();
    float a = b3[t];
    for (int j = 0; j < 201; ++j) a = fmaf(g[j], W3[j * 256 + t], a);
    h1[t] = fmaxf(a, 0.f);
    __syncthreads();
    if (t < 128) {
        float a2 = b4[t];
        for (int j = 0; j < 256; ++j) a2 = fmaf(h1[j], W4[j * 128 + t], a2);
        h2[t] = fmaxf(a2, 0.f);
    }
    __syncthreads();
    float o = b5[t];
    for (int j = 0; j < 128; ++j) o = fmaf(h2[j], W5[j * 256 + t], o);
    out[(size_t)b * 256 + t] = o;
}

extern "C" void kernel_launch(void* const* d_in, const int* in_sizes, int n_in,
                              void* d_out, int out_size, void* d_ws, size_t ws_size,
                              hipStream_t stream) {
    const float* x  = (const float*)d_in[0];
    const float* W1 = (const float*)d_in[1];
    const float* b1 = (const float*)d_in[2];
    const float* W2 = (const float*)d_in[3];
    const float* b2 = (const float*)d_in[4];
    const float* W3 = (const float*)d_in[5];
    const float* b3 = (const float*)d_in[6];
    const float* W4 = (const float*)d_in[7];
    const float* b4 = (const float*)d_in[8];
    const float* W5 = (const float*)d_in[9];
    const float* b5 = (const float*)d_in[10];
    float* out = (float*)d_out;
    float* ws  = (float*)d_ws;

    init_ws_kernel<<<dim3(R1_WORDS / TPB), TPB, 0, stream>>>((unsigned*)ws);
    pass1_kernel<<<dim3(BATCH, P1_CHUNKS), TPB, 0, stream>>>(x, W1, b1, W2, b2, ws);
    eigh_kernel<<<dim3(4), 64, 0, stream>>>(ws);
    pass2_kernel<<<dim3(BATCH, P2_CHUNKS), TPB, 0, stream>>>(x, ws);
    final_kernel<<<dim3(BATCH), TPB, 0, stream>>>(W3, b3, W4, b4, W5, b5, ws, out);
}